// Round 20
// baseline (604.135 us; speedup 1.0000x reference)
//
#include <hip/hip_runtime.h>
#include <hip/hip_bf16.h>
#include <stdint.h>

typedef int v4i __attribute__((ext_vector_type(4)));

#define GM 4096
#define GN 16384
#define GK 4096
#define BM 128
#define BN 128
#define BK 64         // i8 bytes per K-step
#define NT (GK / BK)  // 64 K-tiles

__device__ __forceinline__ void gload16(const void* g, void* l) {
  __builtin_amdgcn_global_load_lds(
      (const __attribute__((address_space(1))) void*)g,
      (__attribute__((address_space(3))) void*)l, 16, 0, 0);
}

// ---------------- per-row dynamic quantization -> fragment-ordered Xq2 ----------------
// Xq2[tm256][kt][f 0..15][lane][16B]: lane l holds row tm256*256 + f*16 + (l&15),
// k = kt*64 + (l>>4)*16 .. +16.   (verbatim R18)
__global__ __launch_bounds__(256) void quant_rows(
    const float* __restrict__ x, int8_t* __restrict__ xq2,
    float* __restrict__ xs, int K) {
  const int row = blockIdx.x;
  const int t = threadIdx.x;
  const float4* src = (const float4*)(x + (size_t)row * K) + t * 4;
  float4 v[4];
  float m = 0.f;
#pragma unroll
  for (int i = 0; i < 4; ++i) {
    v[i] = src[i];
    m = fmaxf(m, fmaxf(fmaxf(fabsf(v[i].x), fabsf(v[i].y)),
                       fmaxf(fabsf(v[i].z), fabsf(v[i].w))));
  }
#pragma unroll
  for (int off = 1; off < 64; off <<= 1)
    m = fmaxf(m, __shfl_xor(m, off, 64));
  __shared__ float wmax[4];
  if ((t & 63) == 0) wmax[t >> 6] = m;
  __syncthreads();
  const float gm = fmaxf(fmaxf(wmax[0], wmax[1]), fmaxf(wmax[2], wmax[3]));
  const float scale = (gm + 1e-5f) / 127.0f;  // == ref x_scales
  if (t == 0) xs[row] = scale;
  unsigned packed[4];
#pragma unroll
  for (int i = 0; i < 4; ++i) {
    float fv[4] = {v[i].x, v[i].y, v[i].z, v[i].w};
    unsigned p = 0;
#pragma unroll
    for (int j = 0; j < 4; ++j) {
      int q = (int)rintf(fv[j] / scale);  // RNE, matches np.round
      q = max(-128, min(127, q));
      p |= (unsigned)(q & 0xff) << (8 * j);
    }
    packed[i] = p;
  }
  const int tm = row >> 8, f = (row >> 4) & 15, fr = row & 15;
  const int kt = t >> 2, kg = t & 3;
  int8_t* dst =
      xq2 + ((((size_t)(tm * 64 + kt) * 16 + f) * 64) + fr + 16 * kg) * 16;
  *(int4*)dst =
      make_int4((int)packed[0], (int)packed[1], (int)packed[2], (int)packed[3]);
}

// ------- W int32 [K][N] -> Wt2 int8 fragment order, NO LDS (verbatim R18) -------
__global__ __launch_bounds__(256) void transpose_pack(
    const int* __restrict__ W32, int8_t* __restrict__ Wt2, int K, int N) {
  const int t = threadIdx.x;
  const int tn = blockIdx.x;  // 256-col panel
  const int kt = blockIdx.y;  // 64-k tile
  const int nq = t & 63;      // n-quad within panel
  const int kg = t >> 6;      // 16-k group
  const int n0 = tn * 256 + nq * 4;
  const int kb = kt * 64 + kg * 16;

  v4i r[16];
#pragma unroll
  for (int k = 0; k < 16; ++k)
    r[k] = *(const v4i*)(W32 + (size_t)(kb + k) * N + n0);

  int o[4][4];
#pragma unroll
  for (int i = 0; i < 4; ++i)
#pragma unroll
    for (int j = 0; j < 4; ++j)
      o[i][j] = (r[4 * j + 0][i] & 0xff) | ((r[4 * j + 1][i] & 0xff) << 8) |
                ((r[4 * j + 2][i] & 0xff) << 16) | (r[4 * j + 3][i] << 24);

  int8_t* base = Wt2 + (((size_t)(tn * 64 + kt) * 16 + (nq >> 2)) * 64 +
                        4 * (nq & 3) + 16 * kg) * 16;
#pragma unroll
  for (int i = 0; i < 4; ++i)
    *(v4i*)(base + i * 16) = *(v4i*)&o[i][0];
}

// ---- int8 GEMM: 128x128 tile, 8 waves 2Mx4N (64x32/wave, 32-AGPR acc).     ----
// ---- ~90 total regs -> 4 waves/SIMD (2 blocks/CU): TLP does the overlap.   ----
// ---- A: 2-slot fragment-ordered LDS ring; B: direct global->VGPR ring-2.   ----
__global__ __launch_bounds__(512, 4) void gemm_i8(
    const int8_t* __restrict__ Xq2, const int8_t* __restrict__ Wt2,
    const float* __restrict__ xs, const float* __restrict__ wsc,
    const float* __restrict__ bias, float* __restrict__ C) {
  __shared__ __align__(16) int8_t lA[2][8192];  // 16 KB: [slot][frag][lane][16B]

  const int t = threadIdx.x;
  const int lane = t & 63;
  const int w = t >> 6;
  const int wr = w >> 2;  // 0..1 (M half: 64 rows)
  const int wc = w & 3;   // 0..3 (N quarter: 32 cols)
  const int fr = lane & 15;
  const int kg = lane >> 4;

  // bijective XCD swizzle: 4096 blocks = 8 XCD x (32 M x 16 N) rectangles
  const int bid = blockIdx.x;
  const int xcd = bid & 7;
  const int q = bid >> 3;
  const int tm = q & 31;                // 0..31
  const int tn = xcd * 16 + (q >> 5);   // 0..127
  const size_t rowA0 = (size_t)tm * BM;
  const size_t rowB0 = (size_t)tn * BN;

  // A: 128-row panel = frags [(tm&1)*8, +8) of 256-row group tm>>1.
  // Wave w stages frag (tm&1)*8 + w (1 KB) -> LDS local frag w.
  const int8_t* aq = Xq2 + (size_t)(tm >> 1) * 1048576 +
                     ((tm & 1) * 8 + w) * 1024 + (size_t)lane * 16;
  // B: 128-col panel = frags [(tn&1)*8, +8) of col-group tn>>1; wave uses
  // local frags wc*2 + nj.
  const int8_t* bq = Wt2 + (size_t)(tn >> 1) * 1048576 +
                     ((tn & 1) * 8 + wc * 2) * 1024 + (size_t)lane * 16;

  v4i acc[4][2] = {};
  v4i areg[4], breg[2][2];  // breg[slot][nj]

#define LD(dst, ptr)                                        \
  asm volatile("global_load_dwordx4 %0, %1, off"            \
               : "=v"(dst)                                  \
               : "v"(ptr)                                   \
               : "memory")

#define STAGE(KT, S) gload16(aq + (size_t)(KT)*16384, &lA[(S)][0] + w * 1024);
#define LOADB(KT, S)                                        \
  {                                                         \
    const int8_t* bp = bq + (size_t)(KT)*16384;             \
    LD(breg[S][0], bp);                                     \
    LD(breg[S][1], bp + 1024);                              \
  }

  // A fragment read: local frag wr*4 + mi, lane-linear -> conflict-free
#define RD_A(MI, S)                                                        \
  areg[MI] = *(const v4i*)&lA[(S)][(wr * 4 + (MI)) * 1024 + lane * 16];

#define SB __builtin_amdgcn_sched_barrier(0)

#define BODY(T, P)                                                            \
  {                                                                           \
    /* gate: stage(T)+B(T) landed (issued one body ago, L2/L3-hot). */        \
    asm volatile("s_waitcnt vmcnt(0)" ::: "memory");                          \
    __builtin_amdgcn_s_barrier(); /* CU-wide: tile T in slot P; P^1 free */   \
    STAGE(((T) + 1) & (NT - 1), (P) ^ 1);                                     \
    LOADB(((T) + 1) & (NT - 1), (P) ^ 1);                                     \
    SB;                                                                       \
    RD_A(0, P); RD_A(1, P); RD_A(2, P); RD_A(3, P);                           \
    SB;                                                                       \
    asm volatile("s_waitcnt lgkmcnt(2)" ::: "memory"); /* A0,A1 ready */      \
    SB;                                                                       \
    __builtin_amdgcn_s_setprio(1);                                            \
    _Pragma("unroll") for (int mi = 0; mi < 2; ++mi)                          \
        _Pragma("unroll") for (int nj = 0; nj < 2; ++nj)                      \
            acc[mi][nj] = __builtin_amdgcn_mfma_i32_16x16x64_i8(              \
                areg[mi], breg[P][nj], acc[mi][nj], 0, 0, 0);                 \
    __builtin_amdgcn_s_setprio(0);                                            \
    asm volatile("s_waitcnt lgkmcnt(0)" ::: "memory"); /* A2,A3 ready */      \
    SB;                                                                       \
    __builtin_amdgcn_s_setprio(1);                                            \
    _Pragma("unroll") for (int mi = 2; mi < 4; ++mi)                          \
        _Pragma("unroll") for (int nj = 0; nj < 2; ++nj)                      \
            acc[mi][nj] = __builtin_amdgcn_mfma_i32_16x16x64_i8(              \
                areg[mi], breg[P][nj], acc[mi][nj], 0, 0, 0);                 \
    __builtin_amdgcn_s_setprio(0);                                            \
  }

  // prologue: stage tile 0 (A->slot0, B->breg[0])
  STAGE(0, 0);
  LOADB(0, 0);

  for (int kt = 0; kt < NT; kt += 2) {
    BODY(kt, 0);
    BODY(kt + 1, 1);
  }
  // drain wrap-around prefetch so late writebacks can't clobber reused regs
  asm volatile("s_waitcnt vmcnt(0) lgkmcnt(0)" ::: "memory");
  SB;

  // epilogue: dequant + bias -> bf16-round -> f32 store
  // 16x16 C/D: col = lane&15, row = (lane>>4)*4 + reg
#pragma unroll
  for (int nj = 0; nj < 2; ++nj) {
    const int col_l = wc * 32 + nj * 16 + fr;
    const float wsv = wsc[rowB0 + col_l];
    const float bv = bias[rowB0 + col_l];
#pragma unroll
    for (int mi = 0; mi < 4; ++mi) {
#pragma unroll
      for (int r = 0; r < 4; ++r) {
        const size_t row = rowA0 + wr * 64 + mi * 16 + kg * 4 + r;
        const float f = (float)acc[mi][nj][r] * xs[row] * wsv + bv;
        C[row * GN + rowB0 + col_l] = __bfloat162float(__float2bfloat16(f));
      }
    }
  }
}

extern "C" void kernel_launch(void* const* d_in, const int* in_sizes, int n_in,
                              void* d_out, int out_size, void* d_ws, size_t ws_size,
                              hipStream_t stream) {
  const int M = GM, K = GK, N = GN;
  const float* x = (const float*)d_in[0];
  const int* W32 = (const int*)d_in[1];  // harness pushes integer inputs as int32
  const float* wsc = (const float*)d_in[2];
  const float* bias = (const float*)d_in[3];
  float* out = (float*)d_out;  // reference output dtype is float32 (bf16-rounded)

  // workspace layout: xs (16KB) | Xq2 (16MB packed) | Wt2 (64MB packed)
  float* xs = (float*)d_ws;
  int8_t* Xq2 = (int8_t*)d_ws + 16384;
  int8_t* Wt2 = (int8_t*)d_ws + 16384 + (size_t)M * K;

  transpose_pack<<<dim3(N / 256, K / 64), 256, 0, stream>>>(W32, Wt2, K, N);
  quant_rows<<<M, 256, 0, stream>>>(x, Xq2, xs, K);
  gemm_i8<<<dim3((M / BM) * (N / BN)), 512, 0, stream>>>(Xq2, Wt2, xs, wsc, bias,
                                                         out);
}

// Round 22
// 460.512 us; speedup vs baseline: 1.3119x; 1.3119x over previous
//
#include <hip/hip_runtime.h>
#include <hip/hip_bf16.h>
#include <stdint.h>

typedef int v4i __attribute__((ext_vector_type(4)));

#define GM 4096
#define GN 16384
#define GK 4096
#define BM 256
#define BN 256
#define BK 64         // i8 bytes per K-step
#define NT (GK / BK)  // 64 K-tiles

__device__ __forceinline__ void gload16(const void* g, void* l) {
  __builtin_amdgcn_global_load_lds(
      (const __attribute__((address_space(1))) void*)g,
      (__attribute__((address_space(3))) void*)l, 16, 0, 0);
}

// ---------------- per-row dynamic quantization -> fragment-ordered Xq2 ----------------
// Xq2[tm][kt][f 0..15][lane][16B]: lane l holds row tm*256 + f*16 + (l&15),
// k = kt*64 + (l>>4)*16 .. +16.
__global__ __launch_bounds__(256) void quant_rows(
    const float* __restrict__ x, int8_t* __restrict__ xq2,
    float* __restrict__ xs, int K) {
  const int row = blockIdx.x;
  const int t = threadIdx.x;
  const float4* src = (const float4*)(x + (size_t)row * K) + t * 4;
  float4 v[4];
  float m = 0.f;
#pragma unroll
  for (int i = 0; i < 4; ++i) {
    v[i] = src[i];
    m = fmaxf(m, fmaxf(fmaxf(fabsf(v[i].x), fabsf(v[i].y)),
                       fmaxf(fabsf(v[i].z), fabsf(v[i].w))));
  }
#pragma unroll
  for (int off = 1; off < 64; off <<= 1)
    m = fmaxf(m, __shfl_xor(m, off, 64));
  __shared__ float wmax[4];
  if ((t & 63) == 0) wmax[t >> 6] = m;
  __syncthreads();
  const float gm = fmaxf(fmaxf(wmax[0], wmax[1]), fmaxf(wmax[2], wmax[3]));
  const float scale = (gm + 1e-5f) / 127.0f;  // == ref x_scales
  if (t == 0) xs[row] = scale;
  unsigned packed[4];
#pragma unroll
  for (int i = 0; i < 4; ++i) {
    float fv[4] = {v[i].x, v[i].y, v[i].z, v[i].w};
    unsigned p = 0;
#pragma unroll
    for (int j = 0; j < 4; ++j) {
      int q = (int)rintf(fv[j] / scale);  // RNE, matches np.round
      q = max(-128, min(127, q));
      p |= (unsigned)(q & 0xff) << (8 * j);
    }
    packed[i] = p;
  }
  const int tm = row >> 8, f = (row >> 4) & 15, fr = row & 15;
  const int kt = t >> 2, kg = t & 3;
  int8_t* dst =
      xq2 + ((((size_t)(tm * 64 + kt) * 16 + f) * 64) + fr + 16 * kg) * 16;
  *(int4*)dst =
      make_int4((int)packed[0], (int)packed[1], (int)packed[2], (int)packed[3]);
}

// ------- W int32 [K][N] -> Wt2 int8 fragment order, NO LDS (verbatim R18) -------
__global__ __launch_bounds__(256) void transpose_pack(
    const int* __restrict__ W32, int8_t* __restrict__ Wt2, int K, int N) {
  const int t = threadIdx.x;
  const int tn = blockIdx.x;  // 256-col panel
  const int kt = blockIdx.y;  // 64-k tile
  const int nq = t & 63;      // n-quad within panel
  const int kg = t >> 6;      // 16-k group
  const int n0 = tn * 256 + nq * 4;
  const int kb = kt * 64 + kg * 16;

  v4i r[16];
#pragma unroll
  for (int k = 0; k < 16; ++k)
    r[k] = *(const v4i*)(W32 + (size_t)(kb + k) * N + n0);

  int o[4][4];
#pragma unroll
  for (int i = 0; i < 4; ++i)
#pragma unroll
    for (int j = 0; j < 4; ++j)
      o[i][j] = (r[4 * j + 0][i] & 0xff) | ((r[4 * j + 1][i] & 0xff) << 8) |
                ((r[4 * j + 2][i] & 0xff) << 16) | (r[4 * j + 3][i] << 24);

  int8_t* base = Wt2 + (((size_t)(tn * 64 + kt) * 16 + (nq >> 2)) * 64 +
                        4 * (nq & 3) + 16 * kg) * 16;
#pragma unroll
  for (int i = 0; i < 4; ++i)
    *(v4i*)(base + i * 16) = *(v4i*)&o[i][0];
}

// ---- int8 GEMM: 2 K-tiles per barrier, compute-one-behind. Both A and B    ----
// ---- staged via 4-slot fragment-ordered LDS rings; MFMA clusters ungated.  ----
// ---- R22 fix: exactly 32 bodies (T=0,2,...,62) — R21 ran one extra body    ----
// ---- that re-accumulated tiles 0,1.                                        ----
__global__ __launch_bounds__(512, 2) void gemm_i8(
    const int8_t* __restrict__ Xq2, const int8_t* __restrict__ Wt2,
    const float* __restrict__ xs, const float* __restrict__ wsc,
    const float* __restrict__ bias, float* __restrict__ C) {
  __shared__ __align__(16) int8_t lA[4][16384];  // 64 KB
  __shared__ __align__(16) int8_t lB[4][16384];  // 64 KB

  const int t = threadIdx.x;
  const int lane = t & 63;
  const int w = t >> 6;
  const int wr = w >> 2;  // 0..1 (M half: 128 rows)
  const int wc = w & 3;   // 0..3 (N quarter: 64 cols)
  const int fr = lane & 15;
  const int kg = lane >> 4;

  // bijective XCD swizzle: 1024 blocks = 8 XCD x (16 M x 8 N) rectangles
  const int bid = blockIdx.x;
  const int xcd = bid & 7;
  const int q = bid >> 3;
  const int tm = q & 15;
  const int tn = xcd * 8 + (q >> 4);
  const size_t rowA0 = (size_t)tm * BM;
  const size_t rowB0 = (size_t)tn * BN;

  // fragment-ordered sources; wave w stages 1KB chunks 2w, 2w+1 of each tile.
  // global SOURCE per-lane (+lane*16); LDS dest wave-uniform (HW adds lane*16).
  const int8_t* aqB = Xq2 + (size_t)tm * 1048576 + w * 2048 + (size_t)lane * 16;
  const int8_t* bqB = Wt2 + (size_t)tn * 1048576 + w * 2048 + (size_t)lane * 16;
  const int dstO = w * 2048;

#define STAGE_A(KT, SL)                                           \
  {                                                               \
    const int8_t* p = aqB + (size_t)(KT)*16384;                   \
    gload16(p, &lA[(SL)][0] + dstO);                              \
    gload16(p + 1024, &lA[(SL)][0] + dstO + 1024);                \
  }
#define STAGE_B(KT, SL)                                           \
  {                                                               \
    const int8_t* p = bqB + (size_t)(KT)*16384;                   \
    gload16(p, &lB[(SL)][0] + dstO);                              \
    gload16(p + 1024, &lB[(SL)][0] + dstO + 1024);                \
  }

  v4i acc[8][4] = {};
  v4i areg[2][8], breg[2][4];  // register banks 0/1 within each body

  // lane-linear fragment reads -> conflict-free
#define RD_A8(SL, BK_)                                                      \
  _Pragma("unroll") for (int mi = 0; mi < 8; ++mi) areg[BK_][mi] =          \
      *(const v4i*)&lA[(SL)][(wr * 8 + mi) * 1024 + lane * 16];
#define RD_B4(SL, BK_)                                                      \
  _Pragma("unroll") for (int nj = 0; nj < 4; ++nj) breg[BK_][nj] =          \
      *(const v4i*)&lB[(SL)][(wc * 4 + nj) * 1024 + lane * 16];

#define MFMA_ALL(BK_)                                                       \
  __builtin_amdgcn_s_setprio(1);                                            \
  _Pragma("unroll") for (int mi = 0; mi < 8; ++mi)                          \
      _Pragma("unroll") for (int nj = 0; nj < 4; ++nj)                      \
          acc[mi][nj] = __builtin_amdgcn_mfma_i32_16x16x64_i8(              \
              areg[BK_][mi], breg[BK_][nj], acc[mi][nj], 0, 0, 0);          \
  __builtin_amdgcn_s_setprio(0);

#define SB __builtin_amdgcn_sched_barrier(0)

  // BODY over tiles T (slot SL0, bank 0) and T+1 (slot SL1, bank 1);
  // stages tiles T+2,T+3 into SS0,SS1; computes tile T-1 (prev body's bank 1)
  // then tile T.  Leaves tile T+1 in bank 1.
#define BODY(T, SL0, SL1, SS0, SS1, DO_PREV)                                  \
  {                                                                           \
    asm volatile("s_waitcnt vmcnt(0)" ::: "memory"); /* prev stages landed */ \
    __builtin_amdgcn_s_barrier(); /* tiles T,T+1 resident; SS0,SS1 free */    \
    STAGE_A(((T) + 2) & (NT - 1), SS0);                                       \
    STAGE_A(((T) + 3) & (NT - 1), SS1);                                       \
    STAGE_B(((T) + 2) & (NT - 1), SS0);                                       \
    STAGE_B(((T) + 3) & (NT - 1), SS1);                                       \
    SB;                                                                       \
    RD_A8(SL0, 0);                                                            \
    RD_B4(SL0, 0);                                                            \
    SB;                                                                       \
    if (DO_PREV) { MFMA_ALL(1) } /* tile T-1: regs from prev body, ungated */ \
    asm volatile("s_waitcnt lgkmcnt(0)" ::: "memory"); /* bank0 ready */      \
    SB;                                                                       \
    RD_A8(SL1, 1);                                                            \
    RD_B4(SL1, 1);                                                            \
    SB;                                                                       \
    MFMA_ALL(0) /* tile T */                                                  \
    asm volatile("s_waitcnt lgkmcnt(0)" ::: "memory"); /* bank1 ready; all */ \
    SB;         /* LDS reads retired before next barrier */                   \
  }

  // prologue: stage tiles 0,1 (A+B, 8 gloads)
  STAGE_A(0, 0);
  STAGE_A(1, 1);
  STAGE_B(0, 0);
  STAGE_B(1, 1);

  // 32 bodies: T = 0, 2, ..., 62.  Body T computes tiles T-1 and T.
  BODY(0, 0, 1, 2, 3, 0);
  for (int kt = 2; kt < NT - 2; kt += 4) {
    BODY(kt, 2, 3, 0, 1, 1);       // T = 2, 6, ..., 58
    BODY(kt + 2, 0, 1, 2, 3, 1);   // T = 4, 8, ..., 60
  }
  BODY(NT - 2, 2, 3, 0, 1, 1);     // T = 62: computes 61, 62; loads 63->bank1
  // tile 63: bank-1 regs loaded (and lgkm-retired) in body 62
  asm volatile("s_waitcnt vmcnt(0) lgkmcnt(0)" ::: "memory");
  SB;
  MFMA_ALL(1)

  // epilogue: dequant + bias -> bf16-round -> f32 store
  // 16x16 C/D: col = lane&15, row = (lane>>4)*4 + reg
#pragma unroll
  for (int nj = 0; nj < 4; ++nj) {
    const int col_l = wc * 64 + nj * 16 + fr;
    const float wsv = wsc[rowB0 + col_l];
    const float bv = bias[rowB0 + col_l];
#pragma unroll
    for (int mi = 0; mi < 8; ++mi) {
#pragma unroll
      for (int r = 0; r < 4; ++r) {
        const size_t row = rowA0 + wr * 128 + mi * 16 + kg * 4 + r;
        const float f = (float)acc[mi][nj][r] * xs[row] * wsv + bv;
        C[row * GN + rowB0 + col_l] = __bfloat162float(__float2bfloat16(f));
      }
    }
  }
}

extern "C" void kernel_launch(void* const* d_in, const int* in_sizes, int n_in,
                              void* d_out, int out_size, void* d_ws, size_t ws_size,
                              hipStream_t stream) {
  const int M = GM, K = GK, N = GN;
  const float* x = (const float*)d_in[0];
  const int* W32 = (const int*)d_in[1];  // harness pushes integer inputs as int32
  const float* wsc = (const float*)d_in[2];
  const float* bias = (const float*)d_in[3];
  float* out = (float*)d_out;  // reference output dtype is float32 (bf16-rounded)

  // workspace layout: xs (16KB) | Xq2 (16MB packed) | Wt2 (64MB packed)
  float* xs = (float*)d_ws;
  int8_t* Xq2 = (int8_t*)d_ws + 16384;
  int8_t* Wt2 = (int8_t*)d_ws + 16384 + (size_t)M * K;

  transpose_pack<<<dim3(N / 256, K / 64), 256, 0, stream>>>(W32, Wt2, K, N);
  quant_rows<<<M, 256, 0, stream>>>(x, Xq2, xs, K);
  gemm_i8<<<dim3((M / BM) * (N / BN)), 512, 0, stream>>>(Xq2, Wt2, xs, wsc, bias,
                                                         out);
}

// Round 23
// 424.881 us; speedup vs baseline: 1.4219x; 1.0839x over previous
//
#include <hip/hip_runtime.h>
#include <hip/hip_bf16.h>
#include <stdint.h>

typedef int v4i __attribute__((ext_vector_type(4)));
typedef int v16i __attribute__((ext_vector_type(16)));

#define GM 4096
#define GN 16384
#define GK 4096
#define BM 256
#define BN 256
#define BK 64         // i8 bytes per K-step
#define NT (GK / BK)  // 64 K-tiles

__device__ __forceinline__ void gload16(const void* g, void* l) {
  __builtin_amdgcn_global_load_lds(
      (const __attribute__((address_space(1))) void*)g,
      (__attribute__((address_space(3))) void*)l, 16, 0, 0);
}

// ------------- per-row dynamic quantization -> 32x32-fragment-ordered Xq2 -------------
// Xq2[tm][kt][f*2+s][lane][16B]: lane l holds row tm*256 + f*32 + (l&31),
// k-byte = kt*64 + s*32 + (l>>5)*16 .. +16.
__global__ __launch_bounds__(256) void quant_rows(
    const float* __restrict__ x, int8_t* __restrict__ xq2,
    float* __restrict__ xs, int K) {
  const int row = blockIdx.x;
  const int t = threadIdx.x;
  const float4* src = (const float4*)(x + (size_t)row * K) + t * 4;
  float4 v[4];
  float m = 0.f;
#pragma unroll
  for (int i = 0; i < 4; ++i) {
    v[i] = src[i];
    m = fmaxf(m, fmaxf(fmaxf(fabsf(v[i].x), fabsf(v[i].y)),
                       fmaxf(fabsf(v[i].z), fabsf(v[i].w))));
  }
#pragma unroll
  for (int off = 1; off < 64; off <<= 1)
    m = fmaxf(m, __shfl_xor(m, off, 64));
  __shared__ float wmax[4];
  if ((t & 63) == 0) wmax[t >> 6] = m;
  __syncthreads();
  const float gm = fmaxf(fmaxf(wmax[0], wmax[1]), fmaxf(wmax[2], wmax[3]));
  const float scale = (gm + 1e-5f) / 127.0f;  // == ref x_scales
  if (t == 0) xs[row] = scale;
  unsigned packed[4];
#pragma unroll
  for (int i = 0; i < 4; ++i) {
    float fv[4] = {v[i].x, v[i].y, v[i].z, v[i].w};
    unsigned p = 0;
#pragma unroll
    for (int j = 0; j < 4; ++j) {
      int q = (int)rintf(fv[j] / scale);  // RNE, matches np.round
      q = max(-128, min(127, q));
      p |= (unsigned)(q & 0xff) << (8 * j);
    }
    packed[i] = p;
  }
  // thread t owns 16B at k-byte t*16: kt = t>>2, s = (t>>1)&1, h = t&1
  const int tm = row >> 8, f = (row >> 5) & 7, l31 = row & 31;
  const int kt = t >> 2, s = (t >> 1) & 1, h = t & 1;
  int8_t* dst = xq2 + (size_t)(tm * 64 + kt) * 16384 + (f * 2 + s) * 1024 +
                (l31 + 32 * h) * 16;
  *(int4*)dst =
      make_int4((int)packed[0], (int)packed[1], (int)packed[2], (int)packed[3]);
}

// ------- W int32 [K][N] -> Wt2 int8 in 32x32-fragment order, NO LDS -------
// Wt2[tn][kt][f*2+s][lane][16B]: lane l holds col tn*256 + f*32 + (l&31),
// k-byte = kt*64 + s*32 + (l>>5)*16 .. +16.
__global__ __launch_bounds__(256) void transpose_pack(
    const int* __restrict__ W32, int8_t* __restrict__ Wt2, int K, int N) {
  const int t = threadIdx.x;
  const int tn = blockIdx.x;  // 256-col panel
  const int kt = blockIdx.y;  // 64-k tile
  const int nq = t & 63;      // 4-col quad within panel
  const int kg = t >> 6;      // 16-k group 0..3
  const int n0 = tn * 256 + nq * 4;
  const int kb = kt * 64 + kg * 16;

  v4i r[16];
#pragma unroll
  for (int k = 0; k < 16; ++k)
    r[k] = *(const v4i*)(W32 + (size_t)(kb + k) * N + n0);

  int o[4][4];
#pragma unroll
  for (int i = 0; i < 4; ++i)
#pragma unroll
    for (int j = 0; j < 4; ++j)
      o[i][j] = (r[4 * j + 0][i] & 0xff) | ((r[4 * j + 1][i] & 0xff) << 8) |
                ((r[4 * j + 2][i] & 0xff) << 16) | (r[4 * j + 3][i] << 24);

  // col n0+i: f = nq>>3, l31 = (nq&7)*4 + i; k: s = kg>>1, h = kg&1.
  // lanes for i=0..3 consecutive -> 16B-contiguous stores.
  const int f = nq >> 3, s = kg >> 1, h = kg & 1;
  int8_t* base = Wt2 + (size_t)(tn * 64 + kt) * 16384 + (f * 2 + s) * 1024 +
                 ((nq & 7) * 4 + 32 * h) * 16;
#pragma unroll
  for (int i = 0; i < 4; ++i)
    *(v4i*)(base + i * 16) = *(v4i*)&o[i][0];
}

// ---- int8 GEMM: R19 skeleton + 32x32x32 MFMA (4404 TOPS, 16 instr/tile/wave). ----
// ---- A via 2-slot fragment-ordered LDS ring; B direct global->VGPR ring-2;    ----
// ---- compute-one-tile-behind, MFMA clusters ungated, counted vmcnt(4).        ----
__global__ __launch_bounds__(512, 2) void gemm_i8(
    const int8_t* __restrict__ Xq2, const int8_t* __restrict__ Wt2,
    const float* __restrict__ xs, const float* __restrict__ wsc,
    const float* __restrict__ bias, float* __restrict__ C) {
  __shared__ __align__(16) int8_t lA[2][16384];  // 32 KB

  const int t = threadIdx.x;
  const int lane = t & 63;
  const int w = t >> 6;
  const int wr = w >> 2;      // 0..1 (M half: 128 rows)
  const int wc = w & 3;       // 0..3 (N quarter: 64 cols)
  const int l31 = lane & 31;
  const int h = lane >> 5;    // 16B-half selector

  // bijective XCD swizzle: 1024 blocks = 8 XCD x (16 M x 8 N) rectangles
  const int bid = blockIdx.x;
  const int xcd = bid & 7;
  const int q = bid >> 3;
  const int tm = q & 15;
  const int tn = xcd * 8 + (q >> 4);
  const size_t rowA0 = (size_t)tm * BM;
  const size_t rowB0 = (size_t)tn * BN;

  // A tile (16 KB linear, fragment order); wave w stages 1KB chunks 2w, 2w+1.
  const int8_t* aqB = Xq2 + (size_t)tm * 1048576 + w * 2048 + (size_t)lane * 16;
  const int dstO = w * 2048;

#define STAGE(KT, SL)                                             \
  {                                                               \
    const int8_t* p = aqB + (size_t)(KT)*16384;                   \
    gload16(p, &lA[(SL)][0] + dstO);                              \
    gload16(p + 1024, &lA[(SL)][0] + dstO + 1024);                \
  }

  // B: per-wave 32-col frags f = wc*2 + nj, slices s
  const int8_t* bq = Wt2 + (size_t)tn * 1048576 + (wc * 2) * 2048 +
                     (size_t)lane * 16;

  v16i acc[4][2] = {};
  v4i areg[2][4][2], breg[2][2][2];  // [bank][frag][slice]

#define LD(dst, ptr)                                        \
  asm volatile("global_load_dwordx4 %0, %1, off"            \
               : "=v"(dst)                                  \
               : "v"(ptr)                                   \
               : "memory")

#define LOADB(KT, BKr)                                      \
  {                                                         \
    const int8_t* bp = bq + (size_t)(KT)*16384;             \
    LD(breg[BKr][0][0], bp);                                \
    LD(breg[BKr][0][1], bp + 1024);                         \
    LD(breg[BKr][1][0], bp + 2048);                         \
    LD(breg[BKr][1][1], bp + 3072);                         \
  }

  // A reads: local frag index (wr*4+mi)*2+s; lane-linear -> conflict-free
#define RD_A8(SL, BKr)                                                      \
  _Pragma("unroll") for (int mi = 0; mi < 4; ++mi)                          \
      _Pragma("unroll") for (int s = 0; s < 2; ++s)                         \
          areg[BKr][mi][s] = *(const v4i*)&lA[(SL)][                        \
              (((wr * 4 + mi) * 2) + s) * 1024 + lane * 16];

#define MFMA_ALL(BKr)                                                       \
  __builtin_amdgcn_s_setprio(1);                                            \
  _Pragma("unroll") for (int mi = 0; mi < 4; ++mi)                          \
      _Pragma("unroll") for (int nj = 0; nj < 2; ++nj)                      \
          _Pragma("unroll") for (int s = 0; s < 2; ++s)                     \
              acc[mi][nj] = __builtin_amdgcn_mfma_i32_32x32x32_i8(          \
                  areg[BKr][mi][s], breg[BKr][nj][s], acc[mi][nj], 0, 0, 0);\
  __builtin_amdgcn_s_setprio(0);

#define SB __builtin_amdgcn_sched_barrier(0)

  // BODY(T): P = T&1.  Reads tile T (slot P -> bank P); computes tile T-1.
#define BODY(T, P)                                                            \
  {                                                                           \
    asm volatile("s_waitcnt vmcnt(4)" ::: "memory"); /* stage(T) landed */    \
    __builtin_amdgcn_s_barrier(); /* CU-wide: tile T in slot P; P^1 free */   \
    STAGE(((T) + 1) & (NT - 1), ((P) ^ 1));                                   \
    SB;                                                                       \
    RD_A8(P, P);                                                              \
    SB;                                                                       \
    MFMA_ALL((P) ^ 1) /* tile T-1: regs from prev body, ungated */            \
    asm volatile("s_waitcnt lgkmcnt(0)" ::: "memory"); /* bank P complete */  \
    SB;                                                                       \
    LOADB(((T) + 1) & (NT - 1), ((P) ^ 1)); /* breg slot just consumed */     \
    SB;                                                                       \
  }

  // prologue: stage tiles 0,1; B tiles 0,1; drain once; preload tile 0 regs
  STAGE(0, 0);
  STAGE(1, 1);
  LOADB(0, 0);
  LOADB(1, 1);
  asm volatile("s_waitcnt vmcnt(0)" ::: "memory");
  __builtin_amdgcn_s_barrier();
  RD_A8(0, 0);
  asm volatile("s_waitcnt lgkmcnt(0)" ::: "memory");
  SB;

  // bodies T=1..63 (computes tiles 0..62); epilogue computes tile 63
  BODY(1, 1);
  for (int kt = 2; kt < NT; kt += 2) {
    BODY(kt, 0);
    BODY(kt + 1, 1);
  }
  asm volatile("s_waitcnt vmcnt(0) lgkmcnt(0)" ::: "memory");
  SB;
  MFMA_ALL(1)  // tile 63 (bank 1; regs loaded at body 63)

  // epilogue: dequant + bias -> bf16-round -> f32 store
  // 32x32 C/D: col = lane&31, row = (reg&3) + 8*(reg>>2) + 4*(lane>>5)
#pragma unroll
  for (int nj = 0; nj < 2; ++nj) {
    const int col_l = wc * 64 + nj * 32 + l31;
    const float wsv = wsc[rowB0 + col_l];
    const float bv = bias[rowB0 + col_l];
#pragma unroll
    for (int mi = 0; mi < 4; ++mi) {
#pragma unroll
      for (int r = 0; r < 16; ++r) {
        const size_t row =
            rowA0 + wr * 128 + mi * 32 + (r & 3) + 8 * (r >> 2) + 4 * h;
        const float f = (float)acc[mi][nj][r] * xs[row] * wsv + bv;
        C[row * GN + rowB0 + col_l] = __bfloat162float(__float2bfloat16(f));
      }
    }
  }
}

extern "C" void kernel_launch(void* const* d_in, const int* in_sizes, int n_in,
                              void* d_out, int out_size, void* d_ws, size_t ws_size,
                              hipStream_t stream) {
  const int M = GM, K = GK, N = GN;
  const float* x = (const float*)d_in[0];
  const int* W32 = (const int*)d_in[1];  // harness pushes integer inputs as int32
  const float* wsc = (const float*)d_in[2];
  const float* bias = (const float*)d_in[3];
  float* out = (float*)d_out;  // reference output dtype is float32 (bf16-rounded)

  // workspace layout: xs (16KB) | Xq2 (16MB packed) | Wt2 (64MB packed)
  float* xs = (float*)d_ws;
  int8_t* Xq2 = (int8_t*)d_ws + 16384;
  int8_t* Wt2 = (int8_t*)d_ws + 16384 + (size_t)M * K;

  transpose_pack<<<dim3(N / 256, K / 64), 256, 0, stream>>>(W32, Wt2, K, N);
  quant_rows<<<M, 256, 0, stream>>>(x, Xq2, xs, K);
  gemm_i8<<<dim3((M / BM) * (N / BN)), 512, 0, stream>>>(Xq2, Wt2, xs, wsc, bias,
                                                         out);
}

// Round 24
// 411.530 us; speedup vs baseline: 1.4680x; 1.0324x over previous
//
#include <hip/hip_runtime.h>
#include <hip/hip_bf16.h>
#include <stdint.h>

typedef int v4i __attribute__((ext_vector_type(4)));

#define GM 4096
#define GN 16384
#define GK 4096
#define BM 256
#define BN 256
#define BK 64         // i8 bytes per K-step
#define NT (GK / BK)  // 64 K-tiles

__device__ __forceinline__ void gload16(const void* g, void* l) {
  __builtin_amdgcn_global_load_lds(
      (const __attribute__((address_space(1))) void*)g,
      (__attribute__((address_space(3))) void*)l, 16, 0, 0);
}

// ---- fused prep: blocks 0..4095 transpose+pack W, blocks 4096..8191 quantize x ----
// Xq2[tm][kt][f 0..15][lane][16B]: lane l holds row tm*256 + f*16 + (l&15),
//   k = kt*64 + (l>>4)*16 .. +16.
// Wt2[tn][kt][f 0..15][slot][16B], slot = (n&15) + 16*((k>>4)&3).
__global__ __launch_bounds__(256) void prep_fused(
    const float* __restrict__ x, const int* __restrict__ W32,
    int8_t* __restrict__ xq2, float* __restrict__ xs,
    int8_t* __restrict__ Wt2) {
  __shared__ float wmax[4];
  const int bid = blockIdx.x;
  const int t = threadIdx.x;

  if (bid < 4096) {
    // ---------------- transpose+pack (R18 body) ----------------
    const int tn = bid & 63;   // 256-col panel
    const int kt = bid >> 6;   // 64-k tile
    const int nq = t & 63;     // n-quad within panel
    const int kg = t >> 6;     // 16-k group
    const int n0 = tn * 256 + nq * 4;
    const int kb = kt * 64 + kg * 16;

    v4i r[16];
#pragma unroll
    for (int k = 0; k < 16; ++k)
      r[k] = *(const v4i*)(W32 + (size_t)(kb + k) * GN + n0);

    int o[4][4];
#pragma unroll
    for (int i = 0; i < 4; ++i)
#pragma unroll
      for (int j = 0; j < 4; ++j)
        o[i][j] = (r[4 * j + 0][i] & 0xff) | ((r[4 * j + 1][i] & 0xff) << 8) |
                  ((r[4 * j + 2][i] & 0xff) << 16) | (r[4 * j + 3][i] << 24);

    int8_t* base = Wt2 + (((size_t)(tn * 64 + kt) * 16 + (nq >> 2)) * 64 +
                          4 * (nq & 3) + 16 * kg) * 16;
#pragma unroll
    for (int i = 0; i < 4; ++i)
      *(v4i*)(base + i * 16) = *(v4i*)&o[i][0];
  } else {
    // ---------------- per-row quantization (R19 body) ----------------
    const int row = bid - 4096;
    const float4* src = (const float4*)(x + (size_t)row * GK) + t * 4;
    float4 v[4];
    float m = 0.f;
#pragma unroll
    for (int i = 0; i < 4; ++i) {
      v[i] = src[i];
      m = fmaxf(m, fmaxf(fmaxf(fabsf(v[i].x), fabsf(v[i].y)),
                         fmaxf(fabsf(v[i].z), fabsf(v[i].w))));
    }
#pragma unroll
    for (int off = 1; off < 64; off <<= 1)
      m = fmaxf(m, __shfl_xor(m, off, 64));
    if ((t & 63) == 0) wmax[t >> 6] = m;
    __syncthreads();
    const float gm = fmaxf(fmaxf(wmax[0], wmax[1]), fmaxf(wmax[2], wmax[3]));
    const float scale = (gm + 1e-5f) / 127.0f;  // == ref x_scales
    if (t == 0) xs[row] = scale;
    unsigned packed[4];
#pragma unroll
    for (int i = 0; i < 4; ++i) {
      float fv[4] = {v[i].x, v[i].y, v[i].z, v[i].w};
      unsigned p = 0;
#pragma unroll
      for (int j = 0; j < 4; ++j) {
        int q = (int)rintf(fv[j] / scale);  // RNE, matches np.round
        q = max(-128, min(127, q));
        p |= (unsigned)(q & 0xff) << (8 * j);
      }
      packed[i] = p;
    }
    const int tm = row >> 8, f = (row >> 4) & 15, fr = row & 15;
    const int kt = t >> 2, kg = t & 3;
    int8_t* dst =
        xq2 + ((((size_t)(tm * 64 + kt) * 16 + f) * 64) + fr + 16 * kg) * 16;
    *(int4*)dst = make_int4((int)packed[0], (int)packed[1], (int)packed[2],
                            (int)packed[3]);
  }
}

// ---- int8 GEMM (verbatim R19, best verified: 300 µs): compute-one-behind,  ----
// ---- 2-slot fragment-ordered A LDS ring, B direct global->VGPR, counted    ----
// ---- vmcnt(4), MFMA clusters ungated.                                      ----
__global__ __launch_bounds__(512, 2) void gemm_i8(
    const int8_t* __restrict__ Xq2, const int8_t* __restrict__ Wt2,
    const float* __restrict__ xs, const float* __restrict__ wsc,
    const float* __restrict__ bias, float* __restrict__ C) {
  __shared__ __align__(16) int8_t lA[2][16384];  // 32 KB: [slot][f][lane][16B]

  const int t = threadIdx.x;
  const int lane = t & 63;
  const int w = t >> 6;
  const int wr = w >> 2;  // 0..1 (M half: 128 rows)
  const int wc = w & 3;   // 0..3 (N quarter: 64 cols)
  const int fr = lane & 15;
  const int kg = lane >> 4;

  // bijective XCD swizzle: 1024 blocks = 8 XCD x (16 M x 8 N) rectangles
  const int bid = blockIdx.x;
  const int xcd = bid & 7;
  const int q = bid >> 3;
  const int tm = q & 15;
  const int tn = xcd * 8 + (q >> 4);
  const size_t rowA0 = (size_t)tm * BM;
  const size_t rowB0 = (size_t)tn * BN;

  // A tile (16 KB linear, fragment order); wave w stages 1KB chunks 2w, 2w+1.
  const int8_t* aqB = Xq2 + (size_t)tm * 1048576 + w * 2048 + (size_t)lane * 16;
  const int dstO = w * 2048;

#define STAGE(KT, SLOT)                                           \
  {                                                               \
    const int8_t* p = aqB + (size_t)(KT)*16384;                   \
    gload16(p, &lA[(SLOT)][0] + dstO);                            \
    gload16(p + 1024, &lA[(SLOT)][0] + dstO + 1024);              \
  }

  // B fragment base for this wave: f = wc*4 + nj
  const int8_t* bq = Wt2 + (size_t)tn * 1048576 + wc * 4096 + (size_t)lane * 16;

  v4i acc[8][4] = {};
  v4i areg[2][8], breg[2][4];  // banks by tile parity

#define LD(dst, ptr)                                        \
  asm volatile("global_load_dwordx4 %0, %1, off"            \
               : "=v"(dst)                                  \
               : "v"(ptr)                                   \
               : "memory")

#define LOADB(KT, S)                                        \
  {                                                         \
    const int8_t* bp = bq + (size_t)(KT)*16384;             \
    LD(breg[S][0], bp);                                     \
    LD(breg[S][1], bp + 1024);                              \
    LD(breg[S][2], bp + 2048);                              \
    LD(breg[S][3], bp + 3072);                              \
  }

  // 8 ds_reads of tile in slot P into areg bank P (lane-linear, conflict-free)
#define RD_A8(P)                                                            \
  _Pragma("unroll") for (int mi = 0; mi < 8; ++mi) areg[P][mi] =            \
      *(const v4i*)&lA[(P)][(wr * 8 + mi) * 1024 + lane * 16];

  // 32 ungated MFMAs of the PREVIOUS tile (bank PB) — operands long since ready
#define MFMA_ALL(PB)                                                        \
  __builtin_amdgcn_s_setprio(1);                                            \
  _Pragma("unroll") for (int mi = 0; mi < 8; ++mi)                          \
      _Pragma("unroll") for (int nj = 0; nj < 4; ++nj)                      \
          acc[mi][nj] = __builtin_amdgcn_mfma_i32_16x16x64_i8(              \
              areg[PB][mi], breg[PB][nj], acc[mi][nj], 0, 0, 0);            \
  __builtin_amdgcn_s_setprio(0);

#define SB __builtin_amdgcn_sched_barrier(0)

  // BODY(T): P = T&1.  Reads tile T (slot P -> bank P); computes tile T-1.
#define BODY(T, P)                                                            \
  {                                                                           \
    asm volatile("s_waitcnt vmcnt(4)" ::: "memory"); /* stage(T) landed */    \
    __builtin_amdgcn_s_barrier();                                             \
    STAGE(((T) + 1) & (NT - 1), ((P) ^ 1));                                   \
    SB;                                                                       \
    RD_A8(P);                                                                 \
    SB;                                                                       \
    MFMA_ALL((P) ^ 1); /* tile T-1: no wait — loaded+drained last body */     \
    asm volatile("s_waitcnt lgkmcnt(0)" ::: "memory"); /* bank P complete */  \
    SB;                                                                       \
    LOADB(((T) + 1) & (NT - 1), ((P) ^ 1)); /* breg slot just consumed */     \
    SB;                                                                       \
  }

  // prologue: stage tiles 0,1; B tiles 0,1; drain once; preload tile 0 regs
  STAGE(0, 0);
  STAGE(1, 1);
  LOADB(0, 0);
  LOADB(1, 1);
  asm volatile("s_waitcnt vmcnt(0)" ::: "memory");
  __builtin_amdgcn_s_barrier();
  RD_A8(0);
  asm volatile("s_waitcnt lgkmcnt(0)" ::: "memory");
  SB;

  // bodies T=1..63 (computes tiles 0..62); epilogue computes tile 63
  BODY(1, 1);
  for (int kt = 2; kt < NT; kt += 2) {
    BODY(kt, 0);
    BODY(kt + 1, 1);
  }
  asm volatile("s_waitcnt vmcnt(0) lgkmcnt(0)" ::: "memory");
  SB;
  MFMA_ALL(1);  // tile 63 (bank 1, breg[1] = B(63), loaded at body 62)

  // epilogue: dequant + bias -> bf16-round -> f32 store
  // 16x16 C/D: col = lane&15, row = (lane>>4)*4 + reg
#pragma unroll
  for (int nj = 0; nj < 4; ++nj) {
    const int col_l = wc * 64 + nj * 16 + fr;
    const float wsv = wsc[rowB0 + col_l];
    const float bv = bias[rowB0 + col_l];
#pragma unroll
    for (int mi = 0; mi < 8; ++mi) {
#pragma unroll
      for (int r = 0; r < 4; ++r) {
        const size_t row = rowA0 + wr * 128 + mi * 16 + kg * 4 + r;
        const float f = (float)acc[mi][nj][r] * xs[row] * wsv + bv;
        C[row * GN + rowB0 + col_l] = __bfloat162float(__float2bfloat16(f));
      }
    }
  }
}

extern "C" void kernel_launch(void* const* d_in, const int* in_sizes, int n_in,
                              void* d_out, int out_size, void* d_ws, size_t ws_size,
                              hipStream_t stream) {
  const int M = GM, K = GK, N = GN;
  const float* x = (const float*)d_in[0];
  const int* W32 = (const int*)d_in[1];  // harness pushes integer inputs as int32
  const float* wsc = (const float*)d_in[2];
  const float* bias = (const float*)d_in[3];
  float* out = (float*)d_out;  // reference output dtype is float32 (bf16-rounded)

  // workspace layout: xs (16KB) | Xq2 (16MB packed) | Wt2 (64MB packed)
  float* xs = (float*)d_ws;
  int8_t* Xq2 = (int8_t*)d_ws + 16384;
  int8_t* Wt2 = (int8_t*)d_ws + 16384 + (size_t)M * K;

  prep_fused<<<8192, 256, 0, stream>>>(x, W32, Xq2, xs, Wt2);
  gemm_i8<<<dim3((M / BM) * (N / BN)), 512, 0, stream>>>(Xq2, Wt2, xs, wsc, bias,
                                                         out);
}